// Round 8
// baseline (147.070 us; speedup 1.0000x reference)
//
#include <hip/hip_runtime.h>
#include <hip/hip_bf16.h>
#include <stdint.h>

// Problem constants (fixed by setup_inputs)
#define B_   8
#define S_   2048
#define C_   768
#define HID_ 768
#define H_   12
#define KW   9
#define D_   64
#define M_   (B_ * S_)   // 16384 rows
#define PADW 4           // KW/2
#define HK_  108         // H_*KW
#define NPAD 128         // padded N for the attn projection

typedef __attribute__((ext_vector_type(4))) float  floatx4;
typedef __attribute__((ext_vector_type(8))) __bf16 bf16x8;

#define GLD_LDS16(gptr, lptr)                                                  \
    __builtin_amdgcn_global_load_lds(                                          \
        (__attribute__((address_space(1))) void*)(gptr),                       \
        (__attribute__((address_space(3))) void*)(lptr), 16, 0, 0)

#define BARR() do { __builtin_amdgcn_s_barrier();                              \
                    __builtin_amdgcn_sched_barrier(0); } while (0)
#define LGKM0() do { asm volatile("s_waitcnt lgkmcnt(0)" ::: "memory");        \
                     __builtin_amdgcn_sched_barrier(0); } while (0)

// direct global->reg 16B load via inline asm: invisible to the compiler's
// vmcnt bookkeeping, so it folds into our manual counted-vmcnt schedule.
// Consumption is fenced by WAITVM + sched_barrier(0) (rule #18).
static __device__ __forceinline__ bf16x8 gload16(const __hip_bfloat16* p) {
    floatx4 r;
    asm volatile("global_load_dwordx4 %0, %1, off" : "=v"(r) : "v"(p) : "memory");
    union { floatx4 f; bf16x8 b; } u;
    u.f = r;
    return u.b;
}

// ---------------------------------------------------------------------------
// Kernel 0: convert pw_weight and attn_W (zero-padded to 128 rows) to bf16
// ---------------------------------------------------------------------------
__global__ __launch_bounds__(256) void convert_w_kernel(
    const float* __restrict__ pwW, const float* __restrict__ attnW,
    __hip_bfloat16* __restrict__ pwWb, __hip_bfloat16* __restrict__ attnWb)
{
    int i = blockIdx.x * 256 + threadIdx.x;           // grid covers C_*HID_
    if (i < C_ * HID_) pwWb[i] = __float2bfloat16(pwW[i]);
    if (i < NPAD * HID_) {
        int n = i / HID_;
        float v = (n < HK_) ? attnW[i] : 0.0f;
        attnWb[i] = __float2bfloat16(v);
    }
}

// ---------------------------------------------------------------------------
// Kernel 1: depthwise conv1d (K=9, pad 4), sliding-window version.
// ---------------------------------------------------------------------------
#define TSD 16

__global__ __launch_bounds__(256) void dwconv_kernel(
    const float* __restrict__ hidden, const float* __restrict__ dw_w,
    __hip_bfloat16* __restrict__ dw_out)
{
    int idx  = blockIdx.x * 256 + threadIdx.x;   // [0, 196608)
    int hq   = idx % (HID_ / 4);                 // 0..191
    int rest = idx / (HID_ / 4);                 // 0..1023
    int sc   = rest % (S_ / TSD);                // 0..127
    int b    = rest / (S_ / TSD);                // 0..7
    int h    = hq * 4;
    int s0   = sc * TSD;
    size_t base = (size_t)b * S_ * HID_ + h;     // row-0 addr for this (b, h)

    float w[36];
    const float4* wp = reinterpret_cast<const float4*>(dw_w + (size_t)h * KW);
#pragma unroll
    for (int i = 0; i < 9; ++i) {
        float4 t = wp[i];
        w[4 * i + 0] = t.x; w[4 * i + 1] = t.y;
        w[4 * i + 2] = t.z; w[4 * i + 3] = t.w;
    }

    float4 win[KW];
#pragma unroll
    for (int k = 0; k < 8; ++k) {
        int sp = s0 + k - PADW;
        float4 v = {0.f, 0.f, 0.f, 0.f};
        if ((unsigned)sp < (unsigned)S_)
            v = *reinterpret_cast<const float4*>(&hidden[base + (size_t)sp * HID_]);
        win[k] = v;
    }

#pragma unroll
    for (int i = 0; i < TSD; ++i) {
        int sp = s0 + i + PADW;
        float4 nv = {0.f, 0.f, 0.f, 0.f};
        if ((unsigned)sp < (unsigned)S_)
            nv = *reinterpret_cast<const float4*>(&hidden[base + (size_t)sp * HID_]);
        win[8] = nv;

        float a0 = 0.f, a1 = 0.f, a2 = 0.f, a3 = 0.f;
#pragma unroll
        for (int k = 0; k < KW; ++k) {
            a0 += win[k].x * w[k];
            a1 += win[k].y * w[9 + k];
            a2 += win[k].z * w[18 + k];
            a3 += win[k].w * w[27 + k];
        }
        union { __hip_bfloat16 bv[4]; uint2 u; } o;
        o.bv[0] = __float2bfloat16(a0);
        o.bv[1] = __float2bfloat16(a1);
        o.bv[2] = __float2bfloat16(a2);
        o.bv[3] = __float2bfloat16(a3);
        *reinterpret_cast<uint2*>(&dw_out[base + (size_t)(s0 + i) * HID_]) = o.u;

#pragma unroll
        for (int k = 0; k < 8; ++k) win[k] = win[k + 1];
    }
}

// ---------------------------------------------------------------------------
// FUSED kernel v3: block = 32 rows, 256 threads = 4 waves (1r x 4c),
// wave tile 32x64. B (pwWb, 1.18 MB, L2-resident) is loaded DIRECTLY from
// global into double-buffered registers via inline-asm global_load_dwordx4,
// prefetched 1 K-step ahead; only A goes through LDS (XOR-swizzled).
// Per K-step issues: 1 gload_lds (A) + 8 reg-loads (B) = 9 -> vmcnt(9)
// counted schedule identical to v2. Post-barrier chain is now just
// 4 ds_read_b128 + 16 MFMA per wave.
// 3 n-tiles of 256 cols; per n-tile: 12-step BK=64 K-loop, then
// P = (acc1+bias)*query -> bf16 -> swizzled LDS; acc2 += P @ attnW-slice.
// Finale: acc2 -> LDS -> per-(row,h) double softmax -> filt.
// LDS 40 KB: A-dbuf 2x4K @0, P 16K @8192, LG 16K @24576. Grid 512 = 2/CU.
// ---------------------------------------------------------------------------
__global__ __launch_bounds__(256, 2) void fused_gemm_kernel(
    const __hip_bfloat16* __restrict__ A,     // dwb   [M_][HID_]
    const __hip_bfloat16* __restrict__ Bt,    // pwWb  [C_][HID_]
    const __hip_bfloat16* __restrict__ Wt,    // attnWb[NPAD][C_]
    const float* __restrict__ bias,           // sep_b [C_]
    const float* __restrict__ query,          // [M_][C_]
    const float* __restrict__ attn_b,         // [HK_]
    float* __restrict__ filt)                 // [M_*H_][KW]
{
    __shared__ __align__(16) char lds[40960];
    char* Plds = lds + 8192;                  // [32 rows][512 B] bf16 swizzled
    float* LG  = (float*)(lds + 24576);       // [32][128] f32

    const int t    = threadIdx.x;
    const int lane = t & 63;
    const int wave = t >> 6;       // 0..3  (= col group)
    const int l16  = lane & 15, lq = lane >> 4;

    const int row0 = (int)blockIdx.x * 32;

    // A staging: 1 instr/wave/K-step = 1 KB = 8 rows x 128 B, pre-swizzled src
    const int sr8     = lane >> 3;                      // 0..7
    const int srcslot = (lane & 7) ^ sr8;
    const __hip_bfloat16* aS = A + (size_t)(row0 + wave * 8 + sr8) * HID_ + srcslot * 8;

    floatx4 acc2[2][2];
#pragma unroll
    for (int m = 0; m < 2; ++m)
#pragma unroll
        for (int n = 0; n < 2; ++n) acc2[m][n] = (floatx4){0.f, 0.f, 0.f, 0.f};

#define FSTG_A(kt, buf)                                                        \
    GLD_LDS16(aS + (kt) * 64, lds + (buf) * 4096 + wave * 1024)

#define BPRE(kt, PRE) do {                                                     \
    _Pragma("unroll") for (int _nf = 0; _nf < 4; ++_nf)                        \
        _Pragma("unroll") for (int _ks = 0; _ks < 2; ++_ks)                    \
            PRE[_nf][_ks] = gload16(bp[_nf] + (kt) * 64 + _ks * 32);           \
} while (0)

#define STEP(kt, CONS, PRE, cbuf, nbuf, last) do {                             \
    if (!(last)) {                                                             \
        FSTG_A((kt) + 1, nbuf);                                                \
        BPRE((kt) + 1, PRE);                                                   \
        asm volatile("s_waitcnt vmcnt(9)" ::: "memory");                       \
    } else {                                                                   \
        asm volatile("s_waitcnt vmcnt(0)" ::: "memory");                       \
    }                                                                          \
    __builtin_amdgcn_sched_barrier(0);                                         \
    __builtin_amdgcn_s_barrier();                                              \
    {                                                                          \
        const char* _ab = lds + (cbuf) * 4096;                                 \
        bf16x8 _av[2][2];                                                      \
        _Pragma("unroll") for (int _m = 0; _m < 2; ++_m) {                     \
            const int _r = _m * 16 + l16;                                      \
            _Pragma("unroll") for (int _ks = 0; _ks < 2; ++_ks)                \
                _av[_m][_ks] = *(const bf16x8*)(_ab + _r * 128 +               \
                    ((_ks * 64 + lq * 16) ^ ((l16 & 7) << 4)));                \
        }                                                                      \
        __builtin_amdgcn_s_setprio(1);                                         \
        _Pragma("unroll") for (int _m = 0; _m < 2; ++_m)                       \
            _Pragma("unroll") for (int _n = 0; _n < 4; ++_n)                   \
                _Pragma("unroll") for (int _ks = 0; _ks < 2; ++_ks)            \
                    acc1[_m][_n] = __builtin_amdgcn_mfma_f32_16x16x32_bf16(    \
                        _av[_m][_ks], CONS[_n][_ks], acc1[_m][_n], 0, 0, 0);   \
        __builtin_amdgcn_s_setprio(0);                                         \
    }                                                                          \
    LGKM0();                                                                   \
    BARR();                                                                    \
} while (0)

    for (int nt = 0; nt < 3; ++nt) {
        // per-lane B fragment base pointers (4 n-frags; ks/kt offsets added)
        const __hip_bfloat16* bp[4];
#pragma unroll
        for (int nf = 0; nf < 4; ++nf)
            bp[nf] = Bt + (size_t)(nt * 256 + wave * 64 + nf * 16 + l16) * HID_
                        + lq * 8;

        floatx4 acc1[2][4];
#pragma unroll
        for (int m = 0; m < 2; ++m)
#pragma unroll
            for (int n = 0; n < 4; ++n) acc1[m][n] = (floatx4){0.f, 0.f, 0.f, 0.f};

        bf16x8 bregA[4][2], bregB[4][2];

        // prologue: stage A(0) + prefetch B(0) -> 9 outstanding
        FSTG_A(0, 0);
        BPRE(0, bregA);

        for (int kp = 0; kp < 6; ++kp) {
            STEP(2 * kp,     bregA, bregB, 0, 1, false);
            STEP(2 * kp + 1, bregB, bregA, 1, 0, (kp == 5));
        }

        // epilogue: P = (acc1 + bias) * query -> bf16, XOR-swizzled LDS write
#pragma unroll
        for (int m = 0; m < 2; ++m)
#pragma unroll
            for (int n = 0; n < 4; ++n) {
                const int cl   = wave * 64 + n * 16 + l16;   // 0..255
                const int gcol = nt * 256 + cl;
                const float bvv = bias[gcol];
#pragma unroll
                for (int j = 0; j < 4; ++j) {
                    const int row = m * 16 + lq * 4 + j;     // 0..31
                    float v = (acc1[m][n][j] + bvv) *
                              query[(size_t)(row0 + row) * C_ + gcol];
                    __hip_bfloat16 hb = __float2bfloat16(v);
                    *(uint16_t*)(Plds + row * 512 +
                                 ((cl * 2) ^ ((row & 7) << 4))) =
                        *(uint16_t*)&hb;
                }
            }
        LGKM0();
        BARR();                           // P complete

        // gemm2 pass: acc2 += P[32x256] @ W-slice[128 x 256]^T
#pragma unroll
        for (int kk = 0; kk < 8; ++kk) {
            bf16x8 pv[2], wv[2];
#pragma unroll
            for (int m = 0; m < 2; ++m) {
                const int r = m * 16 + l16;
                pv[m] = *(const bf16x8*)(Plds + r * 512 +
                    ((kk * 64 + lq * 16) ^ ((l16 & 7) << 4)));
            }
#pragma unroll
            for (int n = 0; n < 2; ++n) {
                const int wrow = wave * 32 + n * 16 + l16;   // 0..127
                wv[n] = *(const bf16x8*)(Wt + (size_t)wrow * C_ +
                                         nt * 256 + kk * 32 + lq * 8);
            }
#pragma unroll
            for (int m = 0; m < 2; ++m)
#pragma unroll
                for (int n = 0; n < 2; ++n)
                    acc2[m][n] = __builtin_amdgcn_mfma_f32_16x16x32_bf16(
                        pv[m], wv[n], acc2[m][n], 0, 0, 0);
        }
        LGKM0();
        BARR();                           // P reads done; next nt may overwrite
    }
#undef FSTG_A
#undef BPRE
#undef STEP

    // finale: acc2 -> LG, then per-(row,h) double softmax -> filt
#pragma unroll
    for (int m = 0; m < 2; ++m)
#pragma unroll
        for (int n = 0; n < 2; ++n) {
            const int cl = wave * 32 + n * 16 + l16;
#pragma unroll
            for (int j = 0; j < 4; ++j) {
                const int row = m * 16 + lq * 4 + j;
                LG[row * 128 + cl] = acc2[m][n][j];
            }
        }
    LGKM0();
    BARR();

    for (int id = t; id < 32 * H_; id += 256) {
        const int row = id / H_;
        const int h   = id - row * H_;
        float v[KW];
#pragma unroll
        for (int k = 0; k < KW; ++k)
            v[k] = LG[row * 128 + h * KW + k] + attn_b[h * KW + k];
#pragma unroll
        for (int pass = 0; pass < 2; ++pass) {
            float mx = v[0];
#pragma unroll
            for (int k = 1; k < KW; ++k) mx = fmaxf(mx, v[k]);
            float s = 0.f;
#pragma unroll
            for (int k = 0; k < KW; ++k) { v[k] = __expf(v[k] - mx); s += v[k]; }
            float inv = 1.f / s;
#pragma unroll
            for (int k = 0; k < KW; ++k) v[k] *= inv;
        }
        const size_t base = ((size_t)(row0 + row) * H_ + h) * KW;
#pragma unroll
        for (int k = 0; k < KW; ++k) filt[base + k] = v[k];
    }
}

// ---------------------------------------------------------------------------
// Kernel 5: light conv, sliding-window version.
// ---------------------------------------------------------------------------
#define TSL 16
#define SCHK 256   // s per block (16 s-groups x TSL)

__global__ __launch_bounds__(256) void lightconv_kernel(
    const float* __restrict__ value, const float* __restrict__ filt,
    float* __restrict__ out)
{
    __shared__ float fl[SCHK * KW];   // 2304 floats

    const int tid = threadIdx.x;
    const int blk = blockIdx.x;                   // [0, 768)
    const int nSC = S_ / SCHK;                    // 8
    const int b   = blk / (H_ * nSC);
    const int rem = blk % (H_ * nSC);
    const int h   = rem / nSC;
    const int sch = rem % nSC;
    const int S0  = sch * SCHK;

    {
        const size_t r0 = ((size_t)b * S_ + S0) * H_ + h;   // filt row of s=S0
#pragma unroll
        for (int i = 0; i < 9; ++i) {
            int j  = tid + 256 * i;               // 0..2303
            int so = j / KW;
            int k  = j - so * KW;
            fl[j] = filt[(r0 + (size_t)so * H_) * KW + k];
        }
    }
    __syncthreads();

    const int d4 = tid & 15;
    const int sg = tid >> 4;                      // 0..15
    const int s0 = S0 + sg * TSL;
    const size_t vbase = (size_t)b * S_ * C_ + h * D_ + d4 * 4;
    const float* flrow = &fl[(sg * TSL) * KW];

    float4 win[KW];
#pragma unroll
    for (int k = 0; k < 8; ++k) {
        int sp = s0 + k - PADW;
        float4 v = {0.f, 0.f, 0.f, 0.f};
        if ((unsigned)sp < (unsigned)S_)
            v = *reinterpret_cast<const float4*>(&value[vbase + (size_t)sp * C_]);
        win[k] = v;
    }

#pragma unroll
    for (int i = 0; i < TSL; ++i) {
        int sp = s0 + i + PADW;
        float4 nv = {0.f, 0.f, 0.f, 0.f};
        if ((unsigned)sp < (unsigned)S_)
            nv = *reinterpret_cast<const float4*>(&value[vbase + (size_t)sp * C_]);
        win[8] = nv;

        float4 acc = {0.f, 0.f, 0.f, 0.f};
#pragma unroll
        for (int k = 0; k < KW; ++k) {
            float f = flrow[i * KW + k];
            acc.x += win[k].x * f;
            acc.y += win[k].y * f;
            acc.z += win[k].z * f;
            acc.w += win[k].w * f;
        }
        *reinterpret_cast<float4*>(&out[vbase + (size_t)(s0 + i) * C_]) = acc;

#pragma unroll
        for (int k = 0; k < 8; ++k) win[k] = win[k + 1];
    }
}

// ---------------------------------------------------------------------------
extern "C" void kernel_launch(void* const* d_in, const int* in_sizes, int n_in,
                              void* d_out, int out_size, void* d_ws, size_t ws_size,
                              hipStream_t stream)
{
    const float* query  = (const float*)d_in[0];
    const float* value  = (const float*)d_in[1];
    const float* hidden = (const float*)d_in[2];
    const float* dw_w   = (const float*)d_in[3];
    const float* pw_w   = (const float*)d_in[4];
    const float* sep_b  = (const float*)d_in[5];
    const float* attn_W = (const float*)d_in[6];
    const float* attn_b = (const float*)d_in[7];
    float* out = (float*)d_out;

    // workspace layout (all regions fully rewritten every call)
    char* ws = (char*)d_ws;
    __hip_bfloat16* dwb    = (__hip_bfloat16*)(ws);              // 25,165,824 B
    __hip_bfloat16* pwWb   = (__hip_bfloat16*)(ws + 25165824);   //  1,179,648 B
    __hip_bfloat16* attnWb = (__hip_bfloat16*)(ws + 26345472);   //    196,608 B
    float*          filt   = (float*)(ws + 26542080);            //  7,077,888 B
    // total: 33,619,968 B

    convert_w_kernel<<<(C_ * HID_) / 256, 256, 0, stream>>>(pw_w, attn_W, pwWb, attnWb);

    dwconv_kernel<<<(M_ * (HID_ / 4)) / (256 * TSD), 256, 0, stream>>>(hidden, dw_w, dwb);

    fused_gemm_kernel<<<M_ / 32, 256, 0, stream>>>(
        dwb, pwWb, attnWb, sep_b, query, attn_b, filt);

    lightconv_kernel<<<B_ * H_ * (S_ / SCHK), 256, 0, stream>>>(value, filt, out);
}

// Round 9
// 94.067 us; speedup vs baseline: 1.5635x; 1.5635x over previous
//
#include <hip/hip_runtime.h>
#include <hip/hip_bf16.h>
#include <stdint.h>

// Problem constants (fixed by setup_inputs)
#define B_   8
#define S_   2048
#define C_   768
#define HID_ 768
#define H_   12
#define KW   9
#define D_   64
#define M_   (B_ * S_)   // 16384 rows
#define PADW 4           // KW/2
#define HK_  108         // H_*KW
#define NPAD 128         // padded N for the attn projection

typedef __attribute__((ext_vector_type(4))) float  floatx4;
typedef __attribute__((ext_vector_type(8))) __bf16 bf16x8;

#define GLD_LDS16(gptr, lptr)                                                  \
    __builtin_amdgcn_global_load_lds(                                          \
        (__attribute__((address_space(1))) void*)(gptr),                       \
        (__attribute__((address_space(3))) void*)(lptr), 16, 0, 0)

#define BARR() do { __builtin_amdgcn_s_barrier();                              \
                    __builtin_amdgcn_sched_barrier(0); } while (0)
#define LGKM0() do { asm volatile("s_waitcnt lgkmcnt(0)" ::: "memory");        \
                     __builtin_amdgcn_sched_barrier(0); } while (0)

// ---------------------------------------------------------------------------
// Kernel 0: convert pw_weight and attn_W (zero-padded to 128 rows) to bf16
// ---------------------------------------------------------------------------
__global__ __launch_bounds__(256) void convert_w_kernel(
    const float* __restrict__ pwW, const float* __restrict__ attnW,
    __hip_bfloat16* __restrict__ pwWb, __hip_bfloat16* __restrict__ attnWb)
{
    int i = blockIdx.x * 256 + threadIdx.x;           // grid covers C_*HID_
    if (i < C_ * HID_) pwWb[i] = __float2bfloat16(pwW[i]);
    if (i < NPAD * HID_) {
        int n = i / HID_;
        float v = (n < HK_) ? attnW[i] : 0.0f;
        attnWb[i] = __float2bfloat16(v);
    }
}

// ---------------------------------------------------------------------------
// Kernel 1: depthwise conv1d (K=9, pad 4), sliding-window version.
// ---------------------------------------------------------------------------
#define TSD 16

__global__ __launch_bounds__(256) void dwconv_kernel(
    const float* __restrict__ hidden, const float* __restrict__ dw_w,
    __hip_bfloat16* __restrict__ dw_out)
{
    int idx  = blockIdx.x * 256 + threadIdx.x;   // [0, 196608)
    int hq   = idx % (HID_ / 4);                 // 0..191
    int rest = idx / (HID_ / 4);                 // 0..1023
    int sc   = rest % (S_ / TSD);                // 0..127
    int b    = rest / (S_ / TSD);                // 0..7
    int h    = hq * 4;
    int s0   = sc * TSD;
    size_t base = (size_t)b * S_ * HID_ + h;     // row-0 addr for this (b, h)

    float w[36];
    const float4* wp = reinterpret_cast<const float4*>(dw_w + (size_t)h * KW);
#pragma unroll
    for (int i = 0; i < 9; ++i) {
        float4 t = wp[i];
        w[4 * i + 0] = t.x; w[4 * i + 1] = t.y;
        w[4 * i + 2] = t.z; w[4 * i + 3] = t.w;
    }

    float4 win[KW];
#pragma unroll
    for (int k = 0; k < 8; ++k) {
        int sp = s0 + k - PADW;
        float4 v = {0.f, 0.f, 0.f, 0.f};
        if ((unsigned)sp < (unsigned)S_)
            v = *reinterpret_cast<const float4*>(&hidden[base + (size_t)sp * HID_]);
        win[k] = v;
    }

#pragma unroll
    for (int i = 0; i < TSD; ++i) {
        int sp = s0 + i + PADW;
        float4 nv = {0.f, 0.f, 0.f, 0.f};
        if ((unsigned)sp < (unsigned)S_)
            nv = *reinterpret_cast<const float4*>(&hidden[base + (size_t)sp * HID_]);
        win[8] = nv;

        float a0 = 0.f, a1 = 0.f, a2 = 0.f, a3 = 0.f;
#pragma unroll
        for (int k = 0; k < KW; ++k) {
            a0 += win[k].x * w[k];
            a1 += win[k].y * w[9 + k];
            a2 += win[k].z * w[18 + k];
            a3 += win[k].w * w[27 + k];
        }
        union { __hip_bfloat16 bv[4]; uint2 u; } o;
        o.bv[0] = __float2bfloat16(a0);
        o.bv[1] = __float2bfloat16(a1);
        o.bv[2] = __float2bfloat16(a2);
        o.bv[3] = __float2bfloat16(a3);
        *reinterpret_cast<uint2*>(&dw_out[base + (size_t)(s0 + i) * HID_]) = o.u;

#pragma unroll
        for (int k = 0; k < 8; ++k) win[k] = win[k + 1];
    }
}

// ---------------------------------------------------------------------------
// FUSED kernel (round-7 v2, reverted from failed v3): block = 32 rows,
// 256 threads = 4 waves (1r x 4c), wave tile 32x64 (0.75 ds_read/MFMA).
// 3 n-tiles of 256 cols; per n-tile a 12-step BK=64 double-buffered K-loop
// (counted vmcnt(9)); A and B staged via global_load_lds, XOR-swizzled
// (pre-swizzled global source + XOR'd ds_read, rule 21).
// After each n-tile: P = (acc1+bias)*query -> bf16 -> swizzled LDS;
// acc2 += P @ attnW-slice (W direct from global, L2-hot).
// Finale: acc2 -> LG (stride 129, conflict-free) -> per-(h,row) double
// softmax -> filt in [B][H][S][KW] layout (contiguous for lightconv).
// LDS 72 KB: A-dbuf 2x4K @0, B-dbuf 2x32K @8192.
// P (16 KB) aliases B-buf0; LG (16.1 KB) aliases B-buf1. Grid 512 = 2/CU.
// ---------------------------------------------------------------------------
__global__ __launch_bounds__(256, 2) void fused_gemm_kernel(
    const __hip_bfloat16* __restrict__ A,     // dwb   [M_][HID_]
    const __hip_bfloat16* __restrict__ Bt,    // pwWb  [C_][HID_]
    const __hip_bfloat16* __restrict__ Wt,    // attnWb[NPAD][C_]
    const float* __restrict__ bias,           // sep_b [C_]
    const float* __restrict__ query,          // [M_][C_]
    const float* __restrict__ attn_b,         // [HK_]
    float* __restrict__ filt)                 // [B_][H_][S_][KW]
{
    __shared__ __align__(16) char lds[73728];
    char* Plds = lds + 8192;                  // aliases B-buf0 (16 KB used)
    float* LG  = (float*)(lds + 8192 + 32768);// aliases B-buf1: [32][129] f32

    const int t    = threadIdx.x;
    const int lane = t & 63;
    const int wave = t >> 6;       // 0..3  (= col group wc)
    const int l16  = lane & 15, lq = lane >> 4;

    const int row0 = (int)blockIdx.x * 32;

    // staging constants: 1 instr = 1 KB = 8 rows of 128 B
    const int sr8     = lane >> 3;                      // 0..7
    const int srcslot = (lane & 7) ^ sr8;               // pre-swizzled source
    // A: 4 KB/step, 1 instr per wave (rows wave*8 + sr8)
    const __hip_bfloat16* aS = A + (size_t)(row0 + wave * 8 + sr8) * HID_ + srcslot * 8;

    floatx4 acc2[2][2];
#pragma unroll
    for (int m = 0; m < 2; ++m)
#pragma unroll
        for (int n = 0; n < 2; ++n) acc2[m][n] = (floatx4){0.f, 0.f, 0.f, 0.f};

    for (int nt = 0; nt < 3; ++nt) {
        // B: 32 KB/step, 8 instrs per wave (rows wave*64 + i*8 + sr8)
        const __hip_bfloat16* bS =
            Bt + (size_t)(nt * 256 + wave * 64 + sr8) * HID_ + srcslot * 8;

        floatx4 acc1[2][4];
#pragma unroll
        for (int m = 0; m < 2; ++m)
#pragma unroll
            for (int n = 0; n < 4; ++n) acc1[m][n] = (floatx4){0.f, 0.f, 0.f, 0.f};

#define FSTG(kt, buf) do {                                                     \
        GLD_LDS16(aS + (kt) * 64, lds + (buf) * 4096 + wave * 1024);           \
        _Pragma("unroll")                                                      \
        for (int _i = 0; _i < 8; ++_i)                                         \
            GLD_LDS16(bS + (size_t)_i * 8 * HID_ + (kt) * 64,                  \
                      lds + 8192 + (buf) * 32768 + wave * 8192 + _i * 1024);   \
    } while (0)

        FSTG(0, 0);
#pragma unroll 2
        for (int kt = 0; kt < 12; ++kt) {
            const int cur = kt & 1;
            if (kt < 11) {
                FSTG(kt + 1, cur ^ 1);
                asm volatile("s_waitcnt vmcnt(9)" ::: "memory");
            } else {
                asm volatile("s_waitcnt vmcnt(0)" ::: "memory");
            }
            __builtin_amdgcn_sched_barrier(0);
            BARR();                       // stage(kt) visible to all waves

            const char* ab = lds + cur * 4096;
            const char* bb = lds + 8192 + cur * 32768;
            bf16x8 av[2][2], bv[4][2];
#pragma unroll
            for (int m = 0; m < 2; ++m) {
                const int r = m * 16 + l16;
#pragma unroll
                for (int ks = 0; ks < 2; ++ks)
                    av[m][ks] = *(const bf16x8*)(ab + r * 128 +
                        ((ks * 64 + lq * 16) ^ ((l16 & 7) << 4)));
            }
#pragma unroll
            for (int n = 0; n < 4; ++n) {
                const int r = wave * 64 + n * 16 + l16;
#pragma unroll
                for (int ks = 0; ks < 2; ++ks)
                    bv[n][ks] = *(const bf16x8*)(bb + r * 128 +
                        ((ks * 64 + lq * 16) ^ ((l16 & 7) << 4)));
            }
            __builtin_amdgcn_s_setprio(1);
#pragma unroll
            for (int m = 0; m < 2; ++m)
#pragma unroll
                for (int n = 0; n < 4; ++n)
#pragma unroll
                    for (int ks = 0; ks < 2; ++ks)
                        acc1[m][n] = __builtin_amdgcn_mfma_f32_16x16x32_bf16(
                            av[m][ks], bv[n][ks], acc1[m][n], 0, 0, 0);
            __builtin_amdgcn_s_setprio(0);
            LGKM0();                      // reads drained before overwrite
            BARR();
        }
#undef FSTG

        // epilogue: P = (acc1 + bias) * query -> bf16, XOR-swizzled LDS write
        // (P aliases B-buf0; all buf reads drained at loop exit)
#pragma unroll
        for (int m = 0; m < 2; ++m)
#pragma unroll
            for (int n = 0; n < 4; ++n) {
                const int cl   = wave * 64 + n * 16 + l16;   // 0..255
                const int gcol = nt * 256 + cl;
                const float bvv = bias[gcol];
#pragma unroll
                for (int j = 0; j < 4; ++j) {
                    const int row = m * 16 + lq * 4 + j;     // 0..31
                    float v = (acc1[m][n][j] + bvv) *
                              query[(size_t)(row0 + row) * C_ + gcol];
                    __hip_bfloat16 hb = __float2bfloat16(v);
                    *(uint16_t*)(Plds + row * 512 +
                                 ((cl * 2) ^ ((row & 7) << 4))) =
                        *(uint16_t*)&hb;
                }
            }
        LGKM0();
        BARR();                           // P complete

        // gemm2 pass: acc2 += P[32x256] @ W-slice[128 x 256]^T
#pragma unroll
        for (int kk = 0; kk < 8; ++kk) {
            bf16x8 pv[2], wv[2];
#pragma unroll
            for (int m = 0; m < 2; ++m) {
                const int r = m * 16 + l16;
                pv[m] = *(const bf16x8*)(Plds + r * 512 +
                    ((kk * 64 + lq * 16) ^ ((l16 & 7) << 4)));
            }
#pragma unroll
            for (int n = 0; n < 2; ++n) {
                const int wrow = wave * 32 + n * 16 + l16;   // 0..127
                wv[n] = *(const bf16x8*)(Wt + (size_t)wrow * C_ +
                                         nt * 256 + kk * 32 + lq * 8);
            }
#pragma unroll
            for (int m = 0; m < 2; ++m)
#pragma unroll
                for (int n = 0; n < 2; ++n)
                    acc2[m][n] = __builtin_amdgcn_mfma_f32_16x16x32_bf16(
                        pv[m], wv[n], acc2[m][n], 0, 0, 0);
        }
        LGKM0();
        BARR();                           // P reads done; next nt may overwrite
    }

    // finale: acc2 -> LG (stride 129: h-outer reads hit 32 distinct banks),
    // then per-(h,row) double softmax -> filt[B][H][S][KW]
#pragma unroll
    for (int m = 0; m < 2; ++m)
#pragma unroll
        for (int n = 0; n < 2; ++n) {
            const int cl = wave * 32 + n * 16 + l16;
#pragma unroll
            for (int j = 0; j < 4; ++j) {
                const int row = m * 16 + lq * 4 + j;
                LG[row * 129 + cl] = acc2[m][n][j];
            }
        }
    LGKM0();
    BARR();

    for (int id = t; id < 32 * H_; id += 256) {
        const int h   = id >> 5;          // 0..11 (h-outer: contiguous writes)
        const int row = id & 31;
        float v[KW];
#pragma unroll
        for (int k = 0; k < KW; ++k)
            v[k] = LG[row * 129 + h * KW + k] + attn_b[h * KW + k];
#pragma unroll
        for (int pass = 0; pass < 2; ++pass) {
            float mx = v[0];
#pragma unroll
            for (int k = 1; k < KW; ++k) mx = fmaxf(mx, v[k]);
            float s = 0.f;
#pragma unroll
            for (int k = 0; k < KW; ++k) { v[k] = __expf(v[k] - mx); s += v[k]; }
            float inv = 1.f / s;
#pragma unroll
            for (int k = 0; k < KW; ++k) v[k] *= inv;
        }
        const int grow = row0 + row;
        const int b    = grow >> 11;      // / S_
        const int s    = grow & (S_ - 1);
        const size_t base = (((size_t)b * H_ + h) * S_ + s) * KW;
#pragma unroll
        for (int k = 0; k < KW; ++k) filt[base + k] = v[k];
    }
}

// ---------------------------------------------------------------------------
// Kernel 5: light conv, sliding-window version.
// filt is [B][H][S][KW] -> block's slab is one contiguous 9216-B run,
// staged as 576 float4 (fully coalesced).
// ---------------------------------------------------------------------------
#define TSL 16
#define SCHK 256   // s per block (16 s-groups x TSL)

__global__ __launch_bounds__(256) void lightconv_kernel(
    const float* __restrict__ value, const float* __restrict__ filt,
    float* __restrict__ out)
{
    __shared__ __align__(16) float fl[SCHK * KW];   // 2304 floats

    const int tid = threadIdx.x;
    const int blk = blockIdx.x;                   // [0, 768)
    const int nSC = S_ / SCHK;                    // 8
    const int b   = blk / (H_ * nSC);
    const int rem = blk % (H_ * nSC);
    const int h   = rem / nSC;
    const int sch = rem % nSC;
    const int S0  = sch * SCHK;

    {
        const float4* src = reinterpret_cast<const float4*>(
            filt + (((size_t)b * H_ + h) * S_ + S0) * KW);
        float4* dst = reinterpret_cast<float4*>(fl);
        for (int j = tid; j < (SCHK * KW) / 4; j += 256)   // 576 float4
            dst[j] = src[j];
    }
    __syncthreads();

    const int d4 = tid & 15;
    const int sg = tid >> 4;                      // 0..15
    const int s0 = S0 + sg * TSL;
    const size_t vbase = (size_t)b * S_ * C_ + h * D_ + d4 * 4;
    const float* flrow = &fl[(sg * TSL) * KW];

    float4 win[KW];
#pragma unroll
    for (int k = 0; k < 8; ++k) {
        int sp = s0 + k - PADW;
        float4 v = {0.f, 0.f, 0.f, 0.f};
        if ((unsigned)sp < (unsigned)S_)
            v = *reinterpret_cast<const float4*>(&value[vbase + (size_t)sp * C_]);
        win[k] = v;
    }

#pragma unroll
    for (int i = 0; i < TSL; ++i) {
        int sp = s0 + i + PADW;
        float4 nv = {0.f, 0.f, 0.f, 0.f};
        if ((unsigned)sp < (unsigned)S_)
            nv = *reinterpret_cast<const float4*>(&value[vbase + (size_t)sp * C_]);
        win[8] = nv;

        float4 acc = {0.f, 0.f, 0.f, 0.f};
#pragma unroll
        for (int k = 0; k < KW; ++k) {
            float f = flrow[i * KW + k];
            acc.x += win[k].x * f;
            acc.y += win[k].y * f;
            acc.z += win[k].z * f;
            acc.w += win[k].w * f;
        }
        *reinterpret_cast<float4*>(&out[vbase + (size_t)(s0 + i) * C_]) = acc;

#pragma unroll
        for (int k = 0; k < 8; ++k) win[k] = win[k + 1];
    }
}

// ---------------------------------------------------------------------------
extern "C" void kernel_launch(void* const* d_in, const int* in_sizes, int n_in,
                              void* d_out, int out_size, void* d_ws, size_t ws_size,
                              hipStream_t stream)
{
    const float* query  = (const float*)d_in[0];
    const float* value  = (const float*)d_in[1];
    const float* hidden = (const float*)d_in[2];
    const float* dw_w   = (const float*)d_in[3];
    const float* pw_w   = (const float*)d_in[4];
    const float* sep_b  = (const float*)d_in[5];
    const float* attn_W = (const float*)d_in[6];
    const float* attn_b = (const float*)d_in[7];
    float* out = (float*)d_out;

    // workspace layout (all regions fully rewritten every call)
    char* ws = (char*)d_ws;
    __hip_bfloat16* dwb    = (__hip_bfloat16*)(ws);              // 25,165,824 B
    __hip_bfloat16* pwWb   = (__hip_bfloat16*)(ws + 25165824);   //  1,179,648 B
    __hip_bfloat16* attnWb = (__hip_bfloat16*)(ws + 26345472);   //    196,608 B
    float*          filt   = (float*)(ws + 26542080);            //  7,077,888 B
    // total: 33,619,968 B

    convert_w_kernel<<<(C_ * HID_) / 256, 256, 0, stream>>>(pw_w, attn_W, pwWb, attnWb);

    dwconv_kernel<<<(M_ * (HID_ / 4)) / (256 * TSD), 256, 0, stream>>>(hidden, dw_w, dwb);

    fused_gemm_kernel<<<M_ / 32, 256, 0, stream>>>(
        dwb, pwWb, attnWb, sep_b, query, attn_b, filt);

    lightconv_kernel<<<B_ * H_ * (S_ / SCHK), 256, 0, stream>>>(value, filt, out);
}